// Round 1
// baseline (351.405 us; speedup 1.0000x reference)
//
#include <hip/hip_runtime.h>
#include <stdint.h>

#define TOKENS 8192
#define INF    4096
#define OUTF   4096

typedef __bf16 bf16x8 __attribute__((ext_vector_type(8)));
typedef float  f32x4  __attribute__((ext_vector_type(4)));

// ---------- fp32 -> bf16 (round-to-nearest-even, bit arithmetic) ----------
__device__ __forceinline__ unsigned short f2bf(float f) {
  union { float f; unsigned int u; } v;
  v.f = f;
  unsigned int r = v.u + 0x7fffu + ((v.u >> 16) & 1u);
  return (unsigned short)(r >> 16);
}

__global__ void l2b_conv_x(const float* __restrict__ x,
                           unsigned short* __restrict__ xb, int n4) {
  int idx = blockIdx.x * blockDim.x + threadIdx.x;
  int stride = gridDim.x * blockDim.x;
  for (int i = idx; i < n4; i += stride) {
    float4 v = reinterpret_cast<const float4*>(x)[i];
    ushort4 o;
    o.x = f2bf(v.x); o.y = f2bf(v.y); o.z = f2bf(v.z); o.w = f2bf(v.w);
    reinterpret_cast<ushort4*>(xb)[i] = o;
  }
}

__global__ void l2b_conv_w(const int* __restrict__ w,
                           unsigned short* __restrict__ wb, int n4) {
  int idx = blockIdx.x * blockDim.x + threadIdx.x;
  int stride = gridDim.x * blockDim.x;
  for (int i = idx; i < n4; i += stride) {
    int4 v = reinterpret_cast<const int4*>(w)[i];
    ushort4 o;  // values in {-2,-1,0,1}: exact in bf16
    o.x = f2bf((float)v.x); o.y = f2bf((float)v.y);
    o.z = f2bf((float)v.z); o.w = f2bf((float)v.w);
    reinterpret_cast<ushort4*>(wb)[i] = o;
  }
}

// ---------- async global->LDS, 16B per lane (dest = uniform base + lane*16) --
__device__ __forceinline__ void gload_lds16(const void* g, void* l) {
  auto gp = reinterpret_cast<__attribute__((address_space(1))) unsigned int*>(
      reinterpret_cast<uintptr_t>(g));
  auto lp = reinterpret_cast<__attribute__((address_space(3))) unsigned int*>(
      reinterpret_cast<uintptr_t>(l));
  __builtin_amdgcn_global_load_lds(gp, lp, 16, 0, 0);
}

// ---------- bf16 MFMA GEMM: C[t][o] = sum_k A[t][k]*B[o][k]; m97 structure ---
// 128x128 tile, 4 waves (2x2), 4x4 fragments of 16x16x32 per wave, BK=32.
__global__ __launch_bounds__(256) void l2b_gemm(
    const unsigned short* __restrict__ A,   // [TOKENS][INF] bf16
    const unsigned short* __restrict__ B,   // [OUTF][INF] bf16 (= B^T layout)
    const float* __restrict__ scale,
    const float* __restrict__ bias,
    float* __restrict__ C) {
  constexpr int K = INF;
  constexpr int N = OUTF;

  __shared__ __align__(16) unsigned short ldsA[128 * 32];  // 8 KiB
  __shared__ __align__(16) unsigned short ldsB[128 * 32];  // 8 KiB

  const int tid  = threadIdx.x;
  const int lane = tid & 63;
  const int wid  = tid >> 6;     // 0..3
  const int wm   = wid >> 1;     // 2x2 wave grid over the 128x128 tile
  const int wn   = wid & 1;

  const int bm = blockIdx.x >> 5;      // M/128 = 64
  const int bn = blockIdx.x & 31;      // N/128 = 32
  const int row0 = bm * 128;
  const int col0 = bn * 128;

  const int lr = lane >> 4;            // 0..3  (k-block / acc row group)
  const int lc = lane & 15;            // 0..15 (fragment row/col)

  f32x4 acc[4][4] = {};

  for (int k0 = 0; k0 < K; k0 += 32) {
    // ---- stage A,B tiles [128][32] bf16 into LDS (linear layout) ----
#pragma unroll
    for (int i = 0; i < 2; ++i) {
      const int idx = i * 256 + tid;       // 0..511, 16B chunk id
      const int r = idx >> 2;              // tile row 0..127
      const int c = (idx & 3) * 8;         // k offset 0/8/16/24
      unsigned short* lbaseA = ldsA + i * 2048 + wid * 512;  // wave-uniform
      unsigned short* lbaseB = ldsB + i * 2048 + wid * 512;
      gload_lds16(A + (size_t)(row0 + r) * K + (k0 + c), lbaseA);
      gload_lds16(B + (size_t)(col0 + r) * K + (k0 + c), lbaseB);
    }
    __syncthreads();   // drains vmcnt before barrier (compiler-inserted)

    // ---- fragments: lane holds row (lc), k = lr*8..lr*8+7 (contiguous) ----
    bf16x8 af[4], bfr[4];
#pragma unroll
    for (int m = 0; m < 4; ++m)
      af[m] = *reinterpret_cast<const bf16x8*>(
          &ldsA[(wm * 64 + m * 16 + lc) * 32 + lr * 8]);
#pragma unroll
    for (int n = 0; n < 4; ++n)
      bfr[n] = *reinterpret_cast<const bf16x8*>(
          &ldsB[(wn * 64 + n * 16 + lc) * 32 + lr * 8]);

#pragma unroll
    for (int m = 0; m < 4; ++m)
#pragma unroll
      for (int n = 0; n < 4; ++n)
        acc[m][n] = __builtin_amdgcn_mfma_f32_16x16x32_bf16(
            af[m], bfr[n], acc[m][n], 0, 0, 0);
    __syncthreads();
  }

  // ---- epilogue: y = acc*scale + bias; C/D layout col=lane&15, row=lr*4+i --
  const float s = scale[0];
#pragma unroll
  for (int n = 0; n < 4; ++n) {
    const int col = col0 + wn * 64 + n * 16 + lc;
    const float bv = bias[col];
#pragma unroll
    for (int m = 0; m < 4; ++m) {
      const int row = row0 + wm * 64 + m * 16 + lr * 4;
#pragma unroll
      for (int i = 0; i < 4; ++i)
        C[(size_t)(row + i) * N + col] = acc[m][n][i] * s + bv;
    }
  }
}

// ---------- fallback (only if workspace too small): naive fp32 --------------
__global__ void l2b_naive(const float* __restrict__ x, const int* __restrict__ w,
                          const float* __restrict__ scale,
                          const float* __restrict__ bias,
                          float* __restrict__ out) {
  const int o = blockIdx.x * blockDim.x + threadIdx.x;
  if (o >= TOKENS * OUTF) return;
  const int t = o / OUTF;
  const int n = o - t * OUTF;
  const float* xr = x + (size_t)t * INF;
  const int* wr = w + (size_t)n * INF;
  float acc = 0.f;
  for (int k = 0; k < INF; ++k) acc += xr[k] * (float)wr[k];
  out[o] = acc * scale[0] + bias[n];
}

extern "C" void kernel_launch(void* const* d_in, const int* in_sizes, int n_in,
                              void* d_out, int out_size, void* d_ws, size_t ws_size,
                              hipStream_t stream) {
  const float* x     = (const float*)d_in[0];
  const int*   wq    = (const int*)d_in[1];
  const float* scale = (const float*)d_in[2];
  const float* bias  = (const float*)d_in[3];
  float* out = (float*)d_out;

  const size_t xbytes = (size_t)TOKENS * INF * 2;  // 64 MiB bf16 x
  const size_t wbytes = (size_t)OUTF * INF * 2;    // 32 MiB bf16 W

  if (ws_size >= xbytes + wbytes) {
    unsigned short* xb = (unsigned short*)d_ws;
    unsigned short* wb = (unsigned short*)((char*)d_ws + xbytes);
    l2b_conv_x<<<2048, 256, 0, stream>>>(x, xb, TOKENS * INF / 4);
    l2b_conv_w<<<2048, 256, 0, stream>>>(wq, wb, OUTF * INF / 4);
    l2b_gemm<<<dim3((TOKENS / 128) * (OUTF / 128)), 256, 0, stream>>>(
        xb, wb, scale, bias, out);
  } else {
    l2b_naive<<<(TOKENS * OUTF + 255) / 256, 256, 0, stream>>>(
        x, wq, scale, bias, out);
  }
}